// Round 1
// baseline (983.632 us; speedup 1.0000x reference)
//
#include <hip/hip_runtime.h>
#include <hip/hip_bf16.h>

// ---------------------------------------------------------------------------
// SemanticActor fused forward, bf16 MFMA (gfx950)
// Inputs (fp32): obs(B,55) ag(B,30) g(B,30) phi_w1(80,256) phi_b1(256)
//   phi_w2(256,256) phi_b2(256) rho_w1(256,256) rho_b1(256)
//   mean_w(256,4) mean_b(4) logstd_w(256,4) logstd_b(4)
// Output (fp32): mean(B,4) ++ logstd(B,4)  flat.
// ---------------------------------------------------------------------------

#define B_TOTAL 65536
#define TROWS   64
#define NPAIR   6

typedef __attribute__((ext_vector_type(8))) short s8v;   // 8 x bf16 (4 VGPRs)
typedef __attribute__((ext_vector_type(4))) float f4v;   // MFMA C/D

__constant__ int c_IND[2][20] = {
  {0,1,2,3,4,5,6,7,8,9,10,11,12,13,15,16,17,20,21,25},
  {0,1,2,3,4,5,6,7,8,9,14,18,19,22,23,24,26,27,28,29}};
__constant__ int c_PI[6] = {0,0,1,1,2,2};
__constant__ int c_PJ[6] = {1,2,0,2,0,1};
__constant__ int c_PF[6] = {0,0,1,0,1,1};

// ---- prep: transpose weights to (N,K) bf16, pad K 80->96 and heads N 8->16 ---
__global__ void prep_weights(const float* __restrict__ phi_w1,
                             const float* __restrict__ phi_w2,
                             const float* __restrict__ rho_w1,
                             const float* __restrict__ mean_w,
                             const float* __restrict__ logstd_w,
                             __hip_bfloat16* __restrict__ W1t,
                             __hip_bfloat16* __restrict__ W2t,
                             __hip_bfloat16* __restrict__ W3t,
                             __hip_bfloat16* __restrict__ W4t) {
  const int i = blockIdx.x * blockDim.x + threadIdx.x;
  const int stride = gridDim.x * blockDim.x;
  for (int idx = i; idx < 256 * 96; idx += stride) {
    int n = idx / 96, kk = idx - n * 96;
    float v = (kk < 80) ? phi_w1[kk * 256 + n] : 0.0f;
    W1t[idx] = __float2bfloat16(v);
  }
  for (int idx = i; idx < 256 * 256; idx += stride) {
    int n = idx >> 8, k = idx & 255;
    W2t[idx] = __float2bfloat16(phi_w2[k * 256 + n]);
    W3t[idx] = __float2bfloat16(rho_w1[k * 256 + n]);
  }
  for (int idx = i; idx < 16 * 256; idx += stride) {
    int n = idx >> 8, k = idx & 255;
    float v = (n < 4) ? mean_w[k * 4 + n]
            : (n < 8) ? logstd_w[k * 4 + (n - 4)] : 0.0f;
    W4t[idx] = __float2bfloat16(v);
  }
}

// ---- main fused kernel: 512 threads (8 waves), 64 batch rows per block -----
__global__ __launch_bounds__(512)
void actor_main(const float* __restrict__ obs, const float* __restrict__ ag,
                const float* __restrict__ g,
                const __hip_bfloat16* __restrict__ W1t,
                const __hip_bfloat16* __restrict__ W2t,
                const __hip_bfloat16* __restrict__ W3t,
                const __hip_bfloat16* __restrict__ W4t,
                const float* __restrict__ b1, const float* __restrict__ b2,
                const float* __restrict__ b3,
                const float* __restrict__ meanb,
                const float* __restrict__ logstdb,
                float* __restrict__ out) {
  // stride 104 (=80+pad): row stride 208B = 52 banks -> conflict-free b128 reads
  __shared__ __align__(16) __hip_bfloat16 Xs[TROWS][104];
  // stride 264 (=256+8): conflict-free A-frag reads, mild write aliasing
  __shared__ __align__(16) __hip_bfloat16 Hs[TROWS][264];

  const int tid  = threadIdx.x;
  const int lane = tid & 63;
  const int wave = tid >> 6;     // 0..7
  const int rt   = wave & 3;     // row tile (16 rows each)
  const int ch   = wave >> 2;    // col half (128 cols each)
  const int m    = lane & 15;
  const int quad = lane >> 4;
  const int kq   = quad * 8;
  const int r0   = blockIdx.x * TROWS;
  const int colbase = ch * 128;
  const int arow = rt * 16 + m;            // A-fragment row
  const int drow = rt * 16 + quad * 4;     // C/D row base

  // hoist per-lane biases (cols colbase+ct*16+m)
  float b1v[8], b2v[8], b3v[8];
#pragma unroll
  for (int ct = 0; ct < 8; ++ct) {
    int col = colbase + ct * 16 + m;
    b1v[ct] = b1[col];
    b2v[ct] = b2[col];
    b3v[ct] = b3[col];
  }

  f4v agg[8];
#pragma unroll
  for (int ct = 0; ct < 8; ++ct) agg[ct] = f4v{0.f, 0.f, 0.f, 0.f};

  // gather mapping: 8 threads/row, 12 cols each
  const int grow = tid >> 3;
  const int gc0  = (tid & 7) * 12;
  const float* agrow  = ag  + (size_t)(r0 + grow) * 30;
  const float* grow_g = g   + (size_t)(r0 + grow) * 30;
  const float* obsrow = obs + (size_t)(r0 + grow) * 55;

  for (int p = 0; p < NPAIR; ++p) {
    const int oi = c_PI[p], oj = c_PJ[p], f = c_PF[p];
    __syncthreads();  // Xs safe to overwrite (prev GEMM1 done), Hs safe (prev GEMM2 done)
#pragma unroll
    for (int cc = 0; cc < 12; ++cc) {
      int c = gc0 + cc;
      float v;
      if      (c < 20) v = agrow[c_IND[f][c]];
      else if (c < 30) v = obsrow[c - 20];
      else if (c < 50) v = grow_g[c_IND[f][c - 30]];
      else if (c < 65) v = obsrow[10 + 15 * oi + (c - 50)];
      else if (c < 80) v = obsrow[10 + 15 * oj + (c - 65)];
      else             v = 0.0f;
      Xs[grow][c] = __float2bfloat16(v);
    }
    __syncthreads();

    // GEMM1: H = relu(X @ W1^T + b1), K=96
    {
      f4v acc[8];
#pragma unroll
      for (int ct = 0; ct < 8; ++ct) acc[ct] = f4v{0.f, 0.f, 0.f, 0.f};
      for (int ks = 0; ks < 3; ++ks) {
        s8v a = *(const s8v*)&Xs[arow][ks * 32 + kq];
#pragma unroll
        for (int ct = 0; ct < 8; ++ct) {
          int n = colbase + ct * 16 + m;
          s8v b = *(const s8v*)&W1t[(size_t)n * 96 + ks * 32 + kq];
          acc[ct] = __builtin_amdgcn_mfma_f32_16x16x32_bf16(a, b, acc[ct], 0, 0, 0);
        }
      }
#pragma unroll
      for (int ct = 0; ct < 8; ++ct)
#pragma unroll
        for (int r = 0; r < 4; ++r) {
          float v = acc[ct][r] + b1v[ct];
          v = v > 0.f ? v : 0.f;
          Hs[drow + r][colbase + ct * 16 + m] = __float2bfloat16(v);
        }
    }
    __syncthreads();

    // GEMM2: agg += relu(H @ W2^T + b2), K=256
    {
      f4v acc[8];
#pragma unroll
      for (int ct = 0; ct < 8; ++ct) acc[ct] = f4v{0.f, 0.f, 0.f, 0.f};
      for (int ks = 0; ks < 8; ++ks) {
        s8v a = *(const s8v*)&Hs[arow][ks * 32 + kq];
#pragma unroll
        for (int ct = 0; ct < 8; ++ct) {
          int n = colbase + ct * 16 + m;
          s8v b = *(const s8v*)&W2t[(size_t)n * 256 + ks * 32 + kq];
          acc[ct] = __builtin_amdgcn_mfma_f32_16x16x32_bf16(a, b, acc[ct], 0, 0, 0);
        }
      }
#pragma unroll
      for (int ct = 0; ct < 8; ++ct)
#pragma unroll
        for (int r = 0; r < 4; ++r) {
          float v = acc[ct][r] + b2v[ct];
          agg[ct][r] += (v > 0.f ? v : 0.f);
        }
    }
  }

  // stash agg (bf16) into Hs for GEMM3 A-operand
  __syncthreads();
#pragma unroll
  for (int ct = 0; ct < 8; ++ct)
#pragma unroll
    for (int r = 0; r < 4; ++r)
      Hs[drow + r][colbase + ct * 16 + m] = __float2bfloat16(agg[ct][r]);
  __syncthreads();

  // GEMM3: hr = relu(agg @ W3^T + b3), K=256
  f4v acc3[8];
#pragma unroll
  for (int ct = 0; ct < 8; ++ct) acc3[ct] = f4v{0.f, 0.f, 0.f, 0.f};
  for (int ks = 0; ks < 8; ++ks) {
    s8v a = *(const s8v*)&Hs[arow][ks * 32 + kq];
#pragma unroll
    for (int ct = 0; ct < 8; ++ct) {
      int n = colbase + ct * 16 + m;
      s8v b = *(const s8v*)&W3t[(size_t)n * 256 + ks * 32 + kq];
      acc3[ct] = __builtin_amdgcn_mfma_f32_16x16x32_bf16(a, b, acc3[ct], 0, 0, 0);
    }
  }
  __syncthreads();  // done reading agg from Hs
#pragma unroll
  for (int ct = 0; ct < 8; ++ct)
#pragma unroll
    for (int r = 0; r < 4; ++r) {
      float v = acc3[ct][r] + b3v[ct];
      v = v > 0.f ? v : 0.f;
      Hs[drow + r][colbase + ct * 16 + m] = __float2bfloat16(v);
    }
  __syncthreads();

  // GEMM4: heads (64x16 out; cols 0..3 mean, 4..7 logstd) — ch==0 waves only
  if (ch == 0) {
    f4v acc4 = f4v{0.f, 0.f, 0.f, 0.f};
    for (int ks = 0; ks < 8; ++ks) {
      s8v a = *(const s8v*)&Hs[arow][ks * 32 + kq];
      s8v b = *(const s8v*)&W4t[(size_t)m * 256 + ks * 32 + kq];
      acc4 = __builtin_amdgcn_mfma_f32_16x16x32_bf16(a, b, acc4, 0, 0, 0);
    }
    if (m < 8) {
#pragma unroll
      for (int r = 0; r < 4; ++r) {
        int row = r0 + drow + r;
        if (m < 4) {
          out[(size_t)row * 4 + m] = acc4[r] + meanb[m];
        } else {
          float lv = acc4[r] + logstdb[m - 4];
          lv = fminf(fmaxf(lv, -20.0f), 2.0f);
          out[(size_t)B_TOTAL * 4 + (size_t)row * 4 + (m - 4)] = lv;
        }
      }
    }
  }
}

extern "C" void kernel_launch(void* const* d_in, const int* in_sizes, int n_in,
                              void* d_out, int out_size, void* d_ws, size_t ws_size,
                              hipStream_t stream) {
  const float* obs      = (const float*)d_in[0];
  const float* ag       = (const float*)d_in[1];
  const float* g        = (const float*)d_in[2];
  const float* phi_w1   = (const float*)d_in[3];
  const float* phi_b1   = (const float*)d_in[4];
  const float* phi_w2   = (const float*)d_in[5];
  const float* phi_b2   = (const float*)d_in[6];
  const float* rho_w1   = (const float*)d_in[7];
  const float* rho_b1   = (const float*)d_in[8];
  const float* mean_w   = (const float*)d_in[9];
  const float* mean_b   = (const float*)d_in[10];
  const float* logstd_w = (const float*)d_in[11];
  const float* logstd_b = (const float*)d_in[12];
  float* out = (float*)d_out;

  // ws layout (bf16): W1t 256x96 | W2t 256x256 | W3t 256x256 | W4t 16x256
  char* ws = (char*)d_ws;
  __hip_bfloat16* W1t = (__hip_bfloat16*)(ws);
  __hip_bfloat16* W2t = (__hip_bfloat16*)(ws + 49152);
  __hip_bfloat16* W3t = (__hip_bfloat16*)(ws + 49152 + 131072);
  __hip_bfloat16* W4t = (__hip_bfloat16*)(ws + 49152 + 131072 + 131072);

  prep_weights<<<128, 256, 0, stream>>>(phi_w1, phi_w2, rho_w1, mean_w, logstd_w,
                                        W1t, W2t, W3t, W4t);
  actor_main<<<B_TOTAL / TROWS, 512, 0, stream>>>(
      obs, ag, g, W1t, W2t, W3t, W4t, phi_b1, phi_b2, rho_b1,
      mean_b, logstd_b, out);
}

// Round 2
// 427.850 us; speedup vs baseline: 2.2990x; 2.2990x over previous
//
#include <hip/hip_runtime.h>
#include <hip/hip_bf16.h>

// ---------------------------------------------------------------------------
// SemanticActor fused forward, bf16 MFMA (gfx950)
// Round 2: kill register spills (R1: 713 MB scratch writes = whole runtime).
// TROWS 64->32, per-wave tile 128->64 cols: persistent VGPRs ~44, no spill.
// ---------------------------------------------------------------------------

#define B_TOTAL 65536
#define TROWS   32
#define NPAIR   6

typedef __attribute__((ext_vector_type(8))) short s8v;   // 8 x bf16 (4 VGPRs)
typedef __attribute__((ext_vector_type(4))) float f4v;   // MFMA C/D

__constant__ int c_IND[2][20] = {
  {0,1,2,3,4,5,6,7,8,9,10,11,12,13,15,16,17,20,21,25},
  {0,1,2,3,4,5,6,7,8,9,14,18,19,22,23,24,26,27,28,29}};
__constant__ int c_PI[6] = {0,0,1,1,2,2};
__constant__ int c_PJ[6] = {1,2,0,2,0,1};
__constant__ int c_PF[6] = {0,0,1,0,1,1};

// ---- prep: transpose weights to (N,K) bf16, pad K 80->96 and heads N 8->16 ---
__global__ void prep_weights(const float* __restrict__ phi_w1,
                             const float* __restrict__ phi_w2,
                             const float* __restrict__ rho_w1,
                             const float* __restrict__ mean_w,
                             const float* __restrict__ logstd_w,
                             __hip_bfloat16* __restrict__ W1t,
                             __hip_bfloat16* __restrict__ W2t,
                             __hip_bfloat16* __restrict__ W3t,
                             __hip_bfloat16* __restrict__ W4t) {
  const int i = blockIdx.x * blockDim.x + threadIdx.x;
  const int stride = gridDim.x * blockDim.x;
  for (int idx = i; idx < 256 * 96; idx += stride) {
    int n = idx / 96, kk = idx - n * 96;
    float v = (kk < 80) ? phi_w1[kk * 256 + n] : 0.0f;
    W1t[idx] = __float2bfloat16(v);
  }
  for (int idx = i; idx < 256 * 256; idx += stride) {
    int n = idx >> 8, k = idx & 255;
    W2t[idx] = __float2bfloat16(phi_w2[k * 256 + n]);
    W3t[idx] = __float2bfloat16(rho_w1[k * 256 + n]);
  }
  for (int idx = i; idx < 16 * 256; idx += stride) {
    int n = idx >> 8, k = idx & 255;
    float v = (n < 4) ? mean_w[k * 4 + n]
            : (n < 8) ? logstd_w[k * 4 + (n - 4)] : 0.0f;
    W4t[idx] = __float2bfloat16(v);
  }
}

// ---- main fused kernel: 512 threads (8 waves), 32 batch rows per block -----
// waves: rt = wave&1 (16-row tile), ch = wave>>1 (64-col quarter), ct 0..3
__global__ __launch_bounds__(512)
void actor_main(const float* __restrict__ obs, const float* __restrict__ ag,
                const float* __restrict__ g,
                const __hip_bfloat16* __restrict__ W1t,
                const __hip_bfloat16* __restrict__ W2t,
                const __hip_bfloat16* __restrict__ W3t,
                const __hip_bfloat16* __restrict__ W4t,
                const float* __restrict__ b1, const float* __restrict__ b2,
                const float* __restrict__ b3,
                const float* __restrict__ meanb,
                const float* __restrict__ logstdb,
                float* __restrict__ out) {
  // stride 104: row stride 208B = 13 x16B groups (odd) -> <=2-way on b128 reads
  __shared__ __align__(16) __hip_bfloat16 Xs[TROWS][104];
  // stride 264: 33 x16B groups (odd) -> <=2-way (free) on b128 A-frag reads
  __shared__ __align__(16) __hip_bfloat16 Hs[TROWS][264];

  const int tid  = threadIdx.x;
  const int lane = tid & 63;
  const int wave = tid >> 6;     // 0..7
  const int rt   = wave & 1;     // row tile (16 rows each)
  const int ch   = wave >> 1;    // col quarter (64 cols each)
  const int m    = lane & 15;
  const int quad = lane >> 4;
  const int kq   = quad * 8;
  const int r0   = blockIdx.x * TROWS;
  const int colbase = ch * 64;
  const int arow = rt * 16 + m;            // A-fragment row
  const int drow = rt * 16 + quad * 4;     // C/D row base

  // hoist per-lane biases (cols colbase+ct*16+m): 12 VGPRs
  float b1v[4], b2v[4], b3v[4];
#pragma unroll
  for (int ct = 0; ct < 4; ++ct) {
    int col = colbase + ct * 16 + m;
    b1v[ct] = b1[col];
    b2v[ct] = b2[col];
    b3v[ct] = b3[col];
  }

  f4v agg[4];
#pragma unroll
  for (int ct = 0; ct < 4; ++ct) agg[ct] = f4v{0.f, 0.f, 0.f, 0.f};

  // gather mapping: 16 threads/row, 6 cols each (96 = padded K)
  const int grow = tid >> 4;          // 0..31
  const int gc0  = (tid & 15) * 6;    // 0,6,...,90
  const float* agrow  = ag  + (size_t)(r0 + grow) * 30;
  const float* grow_g = g   + (size_t)(r0 + grow) * 30;
  const float* obsrow = obs + (size_t)(r0 + grow) * 55;

  for (int p = 0; p < NPAIR; ++p) {
    const int oi = c_PI[p], oj = c_PJ[p], f = c_PF[p];
    __syncthreads();  // Xs safe to overwrite (prev GEMM1 done), Hs safe (prev GEMM2 done)
#pragma unroll
    for (int cc = 0; cc < 6; ++cc) {
      int c = gc0 + cc;
      float v;
      if      (c < 20) v = agrow[c_IND[f][c]];
      else if (c < 30) v = obsrow[c - 20];
      else if (c < 50) v = grow_g[c_IND[f][c - 30]];
      else if (c < 65) v = obsrow[10 + 15 * oi + (c - 50)];
      else if (c < 80) v = obsrow[10 + 15 * oj + (c - 65)];
      else             v = 0.0f;
      Xs[grow][c] = __float2bfloat16(v);
    }
    __syncthreads();

    // GEMM1: H = relu(X @ W1^T + b1), K=96
    {
      f4v acc[4];
#pragma unroll
      for (int ct = 0; ct < 4; ++ct) acc[ct] = f4v{0.f, 0.f, 0.f, 0.f};
      for (int ks = 0; ks < 3; ++ks) {
        s8v a = *(const s8v*)&Xs[arow][ks * 32 + kq];
#pragma unroll
        for (int ct = 0; ct < 4; ++ct) {
          int n = colbase + ct * 16 + m;
          s8v b = *(const s8v*)&W1t[(size_t)n * 96 + ks * 32 + kq];
          acc[ct] = __builtin_amdgcn_mfma_f32_16x16x32_bf16(a, b, acc[ct], 0, 0, 0);
        }
      }
#pragma unroll
      for (int ct = 0; ct < 4; ++ct)
#pragma unroll
        for (int r = 0; r < 4; ++r) {
          float v = acc[ct][r] + b1v[ct];
          v = v > 0.f ? v : 0.f;
          Hs[drow + r][colbase + ct * 16 + m] = __float2bfloat16(v);
        }
    }
    __syncthreads();

    // GEMM2: agg += relu(H @ W2^T + b2), K=256
    {
      f4v acc[4];
#pragma unroll
      for (int ct = 0; ct < 4; ++ct) acc[ct] = f4v{0.f, 0.f, 0.f, 0.f};
      for (int ks = 0; ks < 8; ++ks) {
        s8v a = *(const s8v*)&Hs[arow][ks * 32 + kq];
#pragma unroll
        for (int ct = 0; ct < 4; ++ct) {
          int n = colbase + ct * 16 + m;
          s8v b = *(const s8v*)&W2t[(size_t)n * 256 + ks * 32 + kq];
          acc[ct] = __builtin_amdgcn_mfma_f32_16x16x32_bf16(a, b, acc[ct], 0, 0, 0);
        }
      }
#pragma unroll
      for (int ct = 0; ct < 4; ++ct)
#pragma unroll
        for (int r = 0; r < 4; ++r) {
          float v = acc[ct][r] + b2v[ct];
          agg[ct][r] += (v > 0.f ? v : 0.f);
        }
    }
  }

  // stash agg (bf16) into Hs for GEMM3 A-operand
  __syncthreads();
#pragma unroll
  for (int ct = 0; ct < 4; ++ct)
#pragma unroll
    for (int r = 0; r < 4; ++r)
      Hs[drow + r][colbase + ct * 16 + m] = __float2bfloat16(agg[ct][r]);
  __syncthreads();

  // GEMM3: hr = relu(agg @ W3^T + b3), K=256
  f4v acc3[4];
#pragma unroll
  for (int ct = 0; ct < 4; ++ct) acc3[ct] = f4v{0.f, 0.f, 0.f, 0.f};
  for (int ks = 0; ks < 8; ++ks) {
    s8v a = *(const s8v*)&Hs[arow][ks * 32 + kq];
#pragma unroll
    for (int ct = 0; ct < 4; ++ct) {
      int n = colbase + ct * 16 + m;
      s8v b = *(const s8v*)&W3t[(size_t)n * 256 + ks * 32 + kq];
      acc3[ct] = __builtin_amdgcn_mfma_f32_16x16x32_bf16(a, b, acc3[ct], 0, 0, 0);
    }
  }
  __syncthreads();  // done reading agg from Hs
#pragma unroll
  for (int ct = 0; ct < 4; ++ct)
#pragma unroll
    for (int r = 0; r < 4; ++r) {
      float v = acc3[ct][r] + b3v[ct];
      v = v > 0.f ? v : 0.f;
      Hs[drow + r][colbase + ct * 16 + m] = __float2bfloat16(v);
    }
  __syncthreads();

  // GEMM4: heads (32x16 out; cols 0..3 mean, 4..7 logstd) — ch==0 waves only
  if (ch == 0) {
    f4v acc4 = f4v{0.f, 0.f, 0.f, 0.f};
    for (int ks = 0; ks < 8; ++ks) {
      s8v a = *(const s8v*)&Hs[arow][ks * 32 + kq];
      s8v b = *(const s8v*)&W4t[(size_t)m * 256 + ks * 32 + kq];
      acc4 = __builtin_amdgcn_mfma_f32_16x16x32_bf16(a, b, acc4, 0, 0, 0);
    }
    if (m < 8) {
#pragma unroll
      for (int r = 0; r < 4; ++r) {
        int row = r0 + drow + r;
        if (m < 4) {
          out[(size_t)row * 4 + m] = acc4[r] + meanb[m];
        } else {
          float lv = acc4[r] + logstdb[m - 4];
          lv = fminf(fmaxf(lv, -20.0f), 2.0f);
          out[(size_t)B_TOTAL * 4 + (size_t)row * 4 + (m - 4)] = lv;
        }
      }
    }
  }
}

extern "C" void kernel_launch(void* const* d_in, const int* in_sizes, int n_in,
                              void* d_out, int out_size, void* d_ws, size_t ws_size,
                              hipStream_t stream) {
  const float* obs      = (const float*)d_in[0];
  const float* ag       = (const float*)d_in[1];
  const float* g        = (const float*)d_in[2];
  const float* phi_w1   = (const float*)d_in[3];
  const float* phi_b1   = (const float*)d_in[4];
  const float* phi_w2   = (const float*)d_in[5];
  const float* phi_b2   = (const float*)d_in[6];
  const float* rho_w1   = (const float*)d_in[7];
  const float* rho_b1   = (const float*)d_in[8];
  const float* mean_w   = (const float*)d_in[9];
  const float* mean_b   = (const float*)d_in[10];
  const float* logstd_w = (const float*)d_in[11];
  const float* logstd_b = (const float*)d_in[12];
  float* out = (float*)d_out;

  // ws layout (bf16): W1t 256x96 | W2t 256x256 | W3t 256x256 | W4t 16x256
  char* ws = (char*)d_ws;
  __hip_bfloat16* W1t = (__hip_bfloat16*)(ws);
  __hip_bfloat16* W2t = (__hip_bfloat16*)(ws + 49152);
  __hip_bfloat16* W3t = (__hip_bfloat16*)(ws + 49152 + 131072);
  __hip_bfloat16* W4t = (__hip_bfloat16*)(ws + 49152 + 131072 + 131072);

  prep_weights<<<128, 256, 0, stream>>>(phi_w1, phi_w2, rho_w1, mean_w, logstd_w,
                                        W1t, W2t, W3t, W4t);
  actor_main<<<B_TOTAL / TROWS, 512, 0, stream>>>(
      obs, ag, g, W1t, W2t, W3t, W4t, phi_b1, phi_b2, rho_b1,
      mean_b, logstd_b, out);
}

// Round 3
// 299.730 us; speedup vs baseline: 3.2817x; 1.4274x over previous
//
#include <hip/hip_runtime.h>
#include <hip/hip_bf16.h>

// ---------------------------------------------------------------------------
// SemanticActor fused forward, bf16 MFMA (gfx950) — Round 3
// R2 diagnosis: latency-bound (MfmaUtil 9%): W2 B-frags re-fetched from L2
// 6x/block + 8-way LDS bank conflicts on A-frag reads + 71us prep kernel.
// Fixes: (1) weights register-resident across pair loop (w1f/w2f loaded once),
// (2) transposed GEMMs (A=weight, B=activation) with frag-major LDS layout:
// conflict-free lane-contiguous ds_read_b128, packed ds_write_b64 epilogues,
// coalesced float4 output stores, (3) coalesced-write frag-major prep.
// ---------------------------------------------------------------------------

#define B_TOTAL 65536
#define TROWS   32
#define NPAIR   6

typedef __attribute__((ext_vector_type(8))) short s8v;   // 8 x bf16 (4 VGPRs)
typedef __attribute__((ext_vector_type(4))) float f4v;   // MFMA C/D

__constant__ int c_IND[2][20] = {
  {0,1,2,3,4,5,6,7,8,9,10,11,12,13,15,16,17,20,21,25},
  {0,1,2,3,4,5,6,7,8,9,14,18,19,22,23,24,26,27,28,29}};
__constant__ int c_PI[6] = {0,0,1,1,2,2};
__constant__ int c_PJ[6] = {1,2,0,2,0,1};
__constant__ int c_PF[6] = {0,0,1,0,1,1};

// Frag-major layout: elem (row,col) of an activation matrix (K cols, KB=K/32
// blocks per 16-row tile) lives at:
//   ((row>>4)*KB + (col>>5))*512 + ((row&15) + 16*((col>>3)&3))*8 + (col&7)
// A wave's MFMA fragment (rt, ks) is then the contiguous 1KB at
//   ((rt*KB + ks)*512 + lane*8).

// ---- prep: weights -> frag-major bf16 (writes coalesced) -------------------
__global__ void prep_weights(const float* __restrict__ phi_w1,
                             const float* __restrict__ phi_w2,
                             const float* __restrict__ rho_w1,
                             const float* __restrict__ mean_w,
                             const float* __restrict__ logstd_w,
                             __hip_bfloat16* __restrict__ W1f,
                             __hip_bfloat16* __restrict__ W2f,
                             __hip_bfloat16* __restrict__ W3f,
                             __hip_bfloat16* __restrict__ W4f) {
  const int i0 = blockIdx.x * blockDim.x + threadIdx.x;
  const int stride = gridDim.x * blockDim.x;
  // W1f: 16 nb x 3 ks blocks, n=256, K=96 (pad 80->96)
  for (int d = i0; d < 24576; d += stride) {
    int j = d & 7, lane = (d >> 3) & 63, blk = d >> 9;
    int nb = blk / 3, ks = blk - nb * 3;
    int n = nb * 16 + (lane & 15), k = ks * 32 + (lane >> 4) * 8 + j;
    float v = (k < 80) ? phi_w1[k * 256 + n] : 0.0f;
    W1f[d] = __float2bfloat16(v);
  }
  // W2f/W3f: 16 nb x 8 ks, 256x256
  for (int d = i0; d < 65536; d += stride) {
    int j = d & 7, lane = (d >> 3) & 63, blk = d >> 9;
    int nb = blk >> 3, ks = blk & 7;
    int n = nb * 16 + (lane & 15), k = ks * 32 + (lane >> 4) * 8 + j;
    W2f[d] = __float2bfloat16(phi_w2[k * 256 + n]);
    W3f[d] = __float2bfloat16(rho_w1[k * 256 + n]);
  }
  // W4f: 1 nb (16 head cols: 0-3 mean, 4-7 logstd, 8-15 zero) x 8 ks
  for (int d = i0; d < 4096; d += stride) {
    int j = d & 7, lane = (d >> 3) & 63, ks = d >> 9;
    int n = lane & 15, k = ks * 32 + (lane >> 4) * 8 + j;
    float v = (n < 4) ? mean_w[k * 4 + n]
            : (n < 8) ? logstd_w[k * 4 + (n - 4)] : 0.0f;
    W4f[d] = __float2bfloat16(v);
  }
}

static __device__ __forceinline__ unsigned pk2(float a, float b) {
  __hip_bfloat162 h = __float22bfloat162_rn(float2{a, b});
  union { __hip_bfloat162 h2; unsigned u; } cv; cv.h2 = h;
  return cv.u;
}

// ---- main: 512 threads (8 waves), 32 rows/block, wave = 32-col slice -------
__global__ __launch_bounds__(512, 2)
void actor_main(const float* __restrict__ obs, const float* __restrict__ ag,
                const float* __restrict__ g,
                const __hip_bfloat16* __restrict__ W1f,
                const __hip_bfloat16* __restrict__ W2f,
                const __hip_bfloat16* __restrict__ W3f,
                const __hip_bfloat16* __restrict__ W4f,
                const float* __restrict__ b1, const float* __restrict__ b2,
                const float* __restrict__ b3,
                const float* __restrict__ meanb,
                const float* __restrict__ logstdb,
                float* __restrict__ out) {
  __shared__ __align__(16) __hip_bfloat16 Xs[2 * 3 * 512];  // 6 KB, K=96
  __shared__ __align__(16) __hip_bfloat16 Hs[2 * 8 * 512];  // 16 KB, K=256

  const int tid  = threadIdx.x;
  const int lane = tid & 63;
  const int w    = tid >> 6;      // wave 0..7 -> cols [32w, 32w+32)
  const int l15  = lane & 15;
  const int quad = lane >> 4;
  const int r0   = blockIdx.x * TROWS;

  // biases as float4 (r=0..3 for this lane's quad), per col-16 slice i
  float4 b1v[2], b2v[2], b3v[2];
#pragma unroll
  for (int i = 0; i < 2; ++i) {
    int col0 = w * 32 + i * 16 + quad * 4;
    b1v[i] = *(const float4*)&b1[col0];
    b2v[i] = *(const float4*)&b2[col0];
    b3v[i] = *(const float4*)&b3[col0];
  }

  // persistent weight fragments (loaded ONCE from L2)
  s8v w1f[3][2], w2f[8][2];
#pragma unroll
  for (int i = 0; i < 2; ++i) {
#pragma unroll
    for (int ks = 0; ks < 3; ++ks)
      w1f[ks][i] = *(const s8v*)&W1f[(((w * 2 + i) * 3 + ks) * 512) + lane * 8];
#pragma unroll
    for (int ks = 0; ks < 8; ++ks)
      w2f[ks][i] = *(const s8v*)&W2f[(((w * 2 + i) * 8 + ks) * 512) + lane * 8];
  }

  f4v agg[2][2];
#pragma unroll
  for (int i = 0; i < 2; ++i)
#pragma unroll
    for (int rt = 0; rt < 2; ++rt) agg[i][rt] = f4v{0.f, 0.f, 0.f, 0.f};

  // gather mapping: 16 threads/row, 6 cols each
  const int grow = tid >> 4;          // 0..31
  const int gc0  = (tid & 15) * 6;
  const float* agrow  = ag  + (size_t)(r0 + grow) * 30;
  const float* grow_g = g   + (size_t)(r0 + grow) * 30;
  const float* obsrow = obs + (size_t)(r0 + grow) * 55;

  // epilogue write base (elems): tile (i, rt) ->
  //  (rt*8 + w)*512 + (l15 + 16*(2i + quad>>1))*8 + 4*(quad&1)
  const int ebase = l15 * 8 + (quad >> 1) * 128 + (quad & 1) * 4;

  for (int p = 0; p < NPAIR; ++p) {
    const int oi = c_PI[p], oj = c_PJ[p], f = c_PF[p];
    __syncthreads();  // prev GEMM1 Xs reads + prev GEMM2 Hs reads complete
#pragma unroll
    for (int cc = 0; cc < 6; ++cc) {
      int c = gc0 + cc;
      float v;
      if      (c < 20) v = agrow[c_IND[f][c]];
      else if (c < 30) v = obsrow[c - 20];
      else if (c < 50) v = grow_g[c_IND[f][c - 30]];
      else if (c < 65) v = obsrow[10 + 15 * oi + (c - 50)];
      else if (c < 80) v = obsrow[10 + 15 * oj + (c - 65)];
      else             v = 0.0f;
      int xa = ((grow >> 4) * 3 + (c >> 5)) * 512 +
               ((grow & 15) + 16 * ((c >> 3) & 3)) * 8 + (c & 7);
      Xs[xa] = __float2bfloat16(v);
    }
    __syncthreads();

    // GEMM1 (transposed): Ht[i][rt] = W1(A) x X(B); K=96
    f4v h[2][2];
#pragma unroll
    for (int i = 0; i < 2; ++i)
#pragma unroll
      for (int rt = 0; rt < 2; ++rt) h[i][rt] = f4v{0.f, 0.f, 0.f, 0.f};
#pragma unroll
    for (int ks = 0; ks < 3; ++ks) {
      s8v xf0 = *(const s8v*)&Xs[(0 * 3 + ks) * 512 + lane * 8];
      s8v xf1 = *(const s8v*)&Xs[(1 * 3 + ks) * 512 + lane * 8];
#pragma unroll
      for (int i = 0; i < 2; ++i) {
        h[i][0] = __builtin_amdgcn_mfma_f32_16x16x32_bf16(w1f[ks][i], xf0, h[i][0], 0, 0, 0);
        h[i][1] = __builtin_amdgcn_mfma_f32_16x16x32_bf16(w1f[ks][i], xf1, h[i][1], 0, 0, 0);
      }
    }
    __syncthreads();  // Hs free for overwrite (all waves past GEMM2 of p-1)
    // epilogue: relu(+b1), pack 4 bf16 -> one b64 LDS write per tile
#pragma unroll
    for (int i = 0; i < 2; ++i)
#pragma unroll
      for (int rt = 0; rt < 2; ++rt) {
        float v0 = fmaxf(h[i][rt][0] + b1v[i].x, 0.f);
        float v1 = fmaxf(h[i][rt][1] + b1v[i].y, 0.f);
        float v2 = fmaxf(h[i][rt][2] + b1v[i].z, 0.f);
        float v3 = fmaxf(h[i][rt][3] + b1v[i].w, 0.f);
        uint2 U; U.x = pk2(v0, v1); U.y = pk2(v2, v3);
        int fa = (rt * 8 + w) * 512 + i * 256 + ebase;
        *reinterpret_cast<uint2*>(&Hs[fa]) = U;
      }
    __syncthreads();

    // GEMM2 (transposed): acc = W2(A) x H(B); K=256; agg += relu(acc + b2)
    f4v a2[2][2];
#pragma unroll
    for (int i = 0; i < 2; ++i)
#pragma unroll
      for (int rt = 0; rt < 2; ++rt) a2[i][rt] = f4v{0.f, 0.f, 0.f, 0.f};
#pragma unroll
    for (int ks = 0; ks < 8; ++ks) {
      s8v hf0 = *(const s8v*)&Hs[(0 * 8 + ks) * 512 + lane * 8];
      s8v hf1 = *(const s8v*)&Hs[(1 * 8 + ks) * 512 + lane * 8];
#pragma unroll
      for (int i = 0; i < 2; ++i) {
        a2[i][0] = __builtin_amdgcn_mfma_f32_16x16x32_bf16(w2f[ks][i], hf0, a2[i][0], 0, 0, 0);
        a2[i][1] = __builtin_amdgcn_mfma_f32_16x16x32_bf16(w2f[ks][i], hf1, a2[i][1], 0, 0, 0);
      }
    }
#pragma unroll
    for (int i = 0; i < 2; ++i)
#pragma unroll
      for (int rt = 0; rt < 2; ++rt) {
        agg[i][rt][0] += fmaxf(a2[i][rt][0] + b2v[i].x, 0.f);
        agg[i][rt][1] += fmaxf(a2[i][rt][1] + b2v[i].y, 0.f);
        agg[i][rt][2] += fmaxf(a2[i][rt][2] + b2v[i].z, 0.f);
        agg[i][rt][3] += fmaxf(a2[i][rt][3] + b2v[i].w, 0.f);
      }
  }

  // load W3 frags (overlaps with barrier + stash below)
  s8v w3f[8][2];
#pragma unroll
  for (int i = 0; i < 2; ++i)
#pragma unroll
    for (int ks = 0; ks < 8; ++ks)
      w3f[ks][i] = *(const s8v*)&W3f[(((w * 2 + i) * 8 + ks) * 512) + lane * 8];

  __syncthreads();  // all GEMM2 Hs reads done
  // stash agg (bf16) into Hs, frag-major
#pragma unroll
  for (int i = 0; i < 2; ++i)
#pragma unroll
    for (int rt = 0; rt < 2; ++rt) {
      uint2 U; U.x = pk2(agg[i][rt][0], agg[i][rt][1]);
      U.y = pk2(agg[i][rt][2], agg[i][rt][3]);
      int fa = (rt * 8 + w) * 512 + i * 256 + ebase;
      *reinterpret_cast<uint2*>(&Hs[fa]) = U;
    }
  __syncthreads();

  // GEMM3 (transposed): hr = relu(W3(A) x agg(B) + b3); K=256
  f4v a3[2][2];
#pragma unroll
  for (int i = 0; i < 2; ++i)
#pragma unroll
    for (int rt = 0; rt < 2; ++rt) a3[i][rt] = f4v{0.f, 0.f, 0.f, 0.f};
#pragma unroll
  for (int ks = 0; ks < 8; ++ks) {
    s8v f0 = *(const s8v*)&Hs[(0 * 8 + ks) * 512 + lane * 8];
    s8v f1 = *(const s8v*)&Hs[(1 * 8 + ks) * 512 + lane * 8];
#pragma unroll
    for (int i = 0; i < 2; ++i) {
      a3[i][0] = __builtin_amdgcn_mfma_f32_16x16x32_bf16(w3f[ks][i], f0, a3[i][0], 0, 0, 0);
      a3[i][1] = __builtin_amdgcn_mfma_f32_16x16x32_bf16(w3f[ks][i], f1, a3[i][1], 0, 0, 0);
    }
  }
  __syncthreads();  // all GEMM3 reads done before overwrite
#pragma unroll
  for (int i = 0; i < 2; ++i)
#pragma unroll
    for (int rt = 0; rt < 2; ++rt) {
      float v0 = fmaxf(a3[i][rt][0] + b3v[i].x, 0.f);
      float v1 = fmaxf(a3[i][rt][1] + b3v[i].y, 0.f);
      float v2 = fmaxf(a3[i][rt][2] + b3v[i].z, 0.f);
      float v3 = fmaxf(a3[i][rt][3] + b3v[i].w, 0.f);
      uint2 U; U.x = pk2(v0, v1); U.y = pk2(v2, v3);
      int fa = (rt * 8 + w) * 512 + i * 256 + ebase;
      *reinterpret_cast<uint2*>(&Hs[fa]) = U;
    }
  __syncthreads();

  // GEMM4: heads. waves 0,1 handle rt=w. D[m=headcol][n=row].
  if (w < 2) {
    f4v a4 = f4v{0.f, 0.f, 0.f, 0.f};
#pragma unroll
    for (int ks = 0; ks < 8; ++ks) {
      s8v w4 = *(const s8v*)&W4f[(ks * 512) + lane * 8];
      s8v hf = *(const s8v*)&Hs[(w * 8 + ks) * 512 + lane * 8];
      a4 = __builtin_amdgcn_mfma_f32_16x16x32_bf16(w4, hf, a4, 0, 0, 0);
    }
    const int row = r0 + w * 16 + l15;
    if (quad == 0) {          // cols 0..3 = mean
      float4 mb = *(const float4*)meanb;
      float4 o;
      o.x = a4[0] + mb.x; o.y = a4[1] + mb.y;
      o.z = a4[2] + mb.z; o.w = a4[3] + mb.w;
      *reinterpret_cast<float4*>(&out[(size_t)row * 4]) = o;
    } else if (quad == 1) {   // cols 4..7 = logstd (clipped)
      float4 lb = *(const float4*)logstdb;
      float4 o;
      o.x = fminf(fmaxf(a4[0] + lb.x, -20.f), 2.f);
      o.y = fminf(fmaxf(a4[1] + lb.y, -20.f), 2.f);
      o.z = fminf(fmaxf(a4[2] + lb.z, -20.f), 2.f);
      o.w = fminf(fmaxf(a4[3] + lb.w, -20.f), 2.f);
      *reinterpret_cast<float4*>(&out[(size_t)B_TOTAL * 4 + (size_t)row * 4]) = o;
    }
  }
}

extern "C" void kernel_launch(void* const* d_in, const int* in_sizes, int n_in,
                              void* d_out, int out_size, void* d_ws, size_t ws_size,
                              hipStream_t stream) {
  const float* obs      = (const float*)d_in[0];
  const float* ag       = (const float*)d_in[1];
  const float* g        = (const float*)d_in[2];
  const float* phi_w1   = (const float*)d_in[3];
  const float* phi_b1   = (const float*)d_in[4];
  const float* phi_w2   = (const float*)d_in[5];
  const float* phi_b2   = (const float*)d_in[6];
  const float* rho_w1   = (const float*)d_in[7];
  const float* rho_b1   = (const float*)d_in[8];
  const float* mean_w   = (const float*)d_in[9];
  const float* mean_b   = (const float*)d_in[10];
  const float* logstd_w = (const float*)d_in[11];
  const float* logstd_b = (const float*)d_in[12];
  float* out = (float*)d_out;

  // ws (bf16, frag-major): W1f 24576 | W2f 65536 | W3f 65536 | W4f 4096 elems
  char* ws = (char*)d_ws;
  __hip_bfloat16* W1f = (__hip_bfloat16*)(ws);
  __hip_bfloat16* W2f = (__hip_bfloat16*)(ws + 49152);
  __hip_bfloat16* W3f = (__hip_bfloat16*)(ws + 49152 + 131072);
  __hip_bfloat16* W4f = (__hip_bfloat16*)(ws + 49152 + 131072 + 131072);

  prep_weights<<<256, 256, 0, stream>>>(phi_w1, phi_w2, rho_w1, mean_w, logstd_w,
                                        W1f, W2f, W3f, W4f);
  actor_main<<<B_TOTAL / TROWS, 512, 0, stream>>>(
      obs, ag, g, W1f, W2f, W3f, W4f, phi_b1, phi_b2, rho_b1,
      mean_b, logstd_b, out);
}

// Round 4
// 241.402 us; speedup vs baseline: 4.0747x; 1.2416x over previous
//
#include <hip/hip_runtime.h>
#include <hip/hip_bf16.h>

// ---------------------------------------------------------------------------
// SemanticActor fused forward, bf16 MFMA (gfx950) — Round 4
// R3 diagnosis: latency-bound on the per-pair gather (scattered global loads
// + c_IND indirection + 4 barriers/pair); bank conflicts were gather writes.
// Fix: permute WEIGHTS not inputs. X_p @ W1 == raw @ W1P[p] where W1P[p] has
// W1's rows scattered to raw-column slots (built in prep, L2-resident).
// Raw input [ag(30)|g(30)|obs(55)|1|0pad] staged to LDS ONCE per block,
// bias folded in as ones-column. Per pair: GEMM1 B-frags straight from LDS,
// A-frags prefetched from L2 (double-buffered), 2 barriers. TROWS 32->64.
// ---------------------------------------------------------------------------

#define B_TOTAL 65536
#define TROWS   64
#define RSTR    136   // rawS row stride elems: 272 B = 17x16B (odd) -> <=2-way

typedef __attribute__((ext_vector_type(8))) short s8v;   // 8 x bf16
typedef __attribute__((ext_vector_type(4))) float f4v;   // MFMA C/D

__constant__ int c_PI[6] = {0,0,1,1,2,2};
__constant__ int c_PJ[6] = {1,2,0,2,0,1};
__constant__ int c_PF[6] = {0,0,1,0,1,1};
// inverse of FIRST_INDS / SECOND_INDS: raw ag/g col -> X col (or -1)
__constant__ int c_INV[2][30] = {
  {0,1,2,3,4,5,6,7,8,9,10,11,12,13,-1,14,15,16,-1,-1,17,18,-1,-1,-1,19,-1,-1,-1,-1},
  {0,1,2,3,4,5,6,7,8,9,-1,-1,-1,-1,10,-1,-1,-1,11,12,-1,-1,13,14,15,-1,16,17,18,19}};

// Frag-major weight layout: frag (nb, ks) is contiguous 1 KB; within it lane
// holds 8 elems: n = nb*16 + (lane&15), k = ks*32 + (lane>>4)*8 + j.

__global__ void prep_weights(const float* __restrict__ phi_w1,
                             const float* __restrict__ phi_b1,
                             const float* __restrict__ phi_w2,
                             const float* __restrict__ rho_w1,
                             const float* __restrict__ mean_w,
                             const float* __restrict__ logstd_w,
                             __hip_bfloat16* __restrict__ W1P,
                             __hip_bfloat16* __restrict__ W2f,
                             __hip_bfloat16* __restrict__ W3f,
                             __hip_bfloat16* __restrict__ W4f) {
  const int i0 = blockIdx.x * blockDim.x + threadIdx.x;
  const int stride = gridDim.x * blockDim.x;
  // W1P: 6 pairs x (16 nb x 4 ks) x 512; K=128 raw cols, row k from inverse map
  for (int d = i0; d < 6 * 32768; d += stride) {
    int p = d >> 15, r = d & 32767;
    int j = r & 7, lane = (r >> 3) & 63, blk = r >> 9;
    int nb = blk >> 2, ks = blk & 3;
    int n = nb * 16 + (lane & 15), k = ks * 32 + (lane >> 4) * 8 + j;
    int f = c_PF[p], oi = c_PI[p], oj = c_PJ[p];
    float v = 0.0f;
    if (k < 30)       { int t = c_INV[f][k];      if (t >= 0) v = phi_w1[t * 256 + n]; }
    else if (k < 60)  { int t = c_INV[f][k - 30]; if (t >= 0) v = phi_w1[(30 + t) * 256 + n]; }
    else if (k < 70)  { v = phi_w1[(20 + k - 60) * 256 + n]; }
    else if (k < 115) { int q = (k - 70) / 15, t = (k - 70) - q * 15;
                        int c = (q == oi) ? 50 + t : (q == oj) ? 65 + t : -1;
                        if (c >= 0) v = phi_w1[c * 256 + n]; }
    else if (k == 115) v = phi_b1[n];   // bias via ones-column
    W1P[d] = __float2bfloat16(v);
  }
  // W2f/W3f: 16 nb x 8 ks, 256x256
  for (int d = i0; d < 65536; d += stride) {
    int j = d & 7, lane = (d >> 3) & 63, blk = d >> 9;
    int nb = blk >> 3, ks = blk & 7;
    int n = nb * 16 + (lane & 15), k = ks * 32 + (lane >> 4) * 8 + j;
    W2f[d] = __float2bfloat16(phi_w2[k * 256 + n]);
    W3f[d] = __float2bfloat16(rho_w1[k * 256 + n]);
  }
  // W4f: 1 nb (16 head cols: 0-3 mean, 4-7 logstd, rest 0) x 8 ks
  for (int d = i0; d < 4096; d += stride) {
    int j = d & 7, lane = (d >> 3) & 63, ks = d >> 9;
    int n = lane & 15, k = ks * 32 + (lane >> 4) * 8 + j;
    float v = (n < 4) ? mean_w[k * 4 + n]
            : (n < 8) ? logstd_w[k * 4 + (n - 4)] : 0.0f;
    W4f[d] = __float2bfloat16(v);
  }
}

static __device__ __forceinline__ unsigned pk2(float a, float b) {
  __hip_bfloat162 h = __float22bfloat162_rn(float2{a, b});
  union { __hip_bfloat162 h2; unsigned u; } cv; cv.h2 = h;
  return cv.u;
}

// ---- main: 512 threads (8 waves), 64 rows/block, wave = 32-col slice -------
__global__ __launch_bounds__(512, 2)
void actor_main(const float* __restrict__ obs, const float* __restrict__ ag,
                const float* __restrict__ g,
                const __hip_bfloat16* __restrict__ W1P,
                const __hip_bfloat16* __restrict__ W2f,
                const __hip_bfloat16* __restrict__ W3f,
                const __hip_bfloat16* __restrict__ W4f,
                const float* __restrict__ b2, const float* __restrict__ b3,
                const float* __restrict__ meanb,
                const float* __restrict__ logstdb,
                float* __restrict__ out) {
  __shared__ __align__(16) __hip_bfloat16 rawS[TROWS * RSTR];  // 17.4 KB
  __shared__ __align__(16) __hip_bfloat16 Hs[4 * 8 * 512];     // 32 KB

  const int tid  = threadIdx.x;
  const int lane = tid & 63;
  const int w    = tid >> 6;      // wave 0..7 -> hidden cols [32w, 32w+32)
  const int l15  = lane & 15;
  const int quad = lane >> 4;
  const int r0   = blockIdx.x * TROWS;

  // biases (GEMM2/GEMM3 epilogues), cols w*32 + i*16 + quad*4 + r
  float4 b2v[2], b3v[2];
#pragma unroll
  for (int i = 0; i < 2; ++i) {
    int col0 = w * 32 + i * 16 + quad * 4;
    b2v[i] = *(const float4*)&b2[col0];
    b3v[i] = *(const float4*)&b3[col0];
  }

  // persistent W2 fragments (once per block)
  s8v w2f[8][2];
#pragma unroll
  for (int i = 0; i < 2; ++i)
#pragma unroll
    for (int ks = 0; ks < 8; ++ks)
      w2f[ks][i] = *(const s8v*)&W2f[(((w * 2 + i) * 8 + ks) * 512) + lane * 8];

  // stage raw input [ag|g|obs|1|0] as bf16, K=128, once per block
  {
    const int row = tid >> 3;           // 0..63
    const int c0  = (tid & 7) * 16;     // 0..112
    const float* agr = ag  + (size_t)(r0 + row) * 30;
    const float* gr  = g   + (size_t)(r0 + row) * 30;
    const float* obr = obs + (size_t)(r0 + row) * 55;
#pragma unroll
    for (int cc = 0; cc < 16; ++cc) {
      int c = c0 + cc;
      float v;
      if      (c < 30)  v = agr[c];
      else if (c < 60)  v = gr[c - 30];
      else if (c < 115) v = obr[c - 60];
      else if (c == 115) v = 1.0f;
      else              v = 0.0f;
      rawS[row * RSTR + c] = __float2bfloat16(v);
    }
  }

  f4v agg[2][4];
#pragma unroll
  for (int i = 0; i < 2; ++i)
#pragma unroll
    for (int rt = 0; rt < 4; ++rt) agg[i][rt] = f4v{0.f, 0.f, 0.f, 0.f};

  // Hs epilogue base: element E(h,b) = (h>>3)*128 + b*8 + (h&7)
  const int ebase = l15 * 8 + (quad >> 1) * 128 + (quad & 1) * 4;

  // prefetch pair 0's W1P frags
  s8v w1b[2][4][2];
#pragma unroll
  for (int i = 0; i < 2; ++i)
#pragma unroll
    for (int ks = 0; ks < 4; ++ks)
      w1b[0][ks][i] = *(const s8v*)&W1P[(((w * 2 + i) * 4 + ks) * 512) + lane * 8];

  __syncthreads();  // rawS staged

#pragma unroll
  for (int p = 0; p < 6; ++p) {
    const int cur = p & 1, nxt = cur ^ 1;

    // GEMM1: h = W1P[p](A) x raw(B); K=128
    f4v h[2][4];
#pragma unroll
    for (int i = 0; i < 2; ++i)
#pragma unroll
      for (int rt = 0; rt < 4; ++rt) h[i][rt] = f4v{0.f, 0.f, 0.f, 0.f};
#pragma unroll
    for (int ks = 0; ks < 4; ++ks) {
      s8v bx[4];
#pragma unroll
      for (int rt = 0; rt < 4; ++rt)
        bx[rt] = *(const s8v*)&rawS[(rt * 16 + l15) * RSTR + ks * 32 + quad * 8];
#pragma unroll
      for (int i = 0; i < 2; ++i)
#pragma unroll
        for (int rt = 0; rt < 4; ++rt)
          h[i][rt] = __builtin_amdgcn_mfma_f32_16x16x32_bf16(w1b[cur][ks][i], bx[rt], h[i][rt], 0, 0, 0);
    }

    // prefetch next pair's W1P frags (hides L2 latency behind barrier+GEMM2)
    if (p < 5) {
      const __hip_bfloat16* base = W1P + (p + 1) * 32768;
#pragma unroll
      for (int i = 0; i < 2; ++i)
#pragma unroll
        for (int ks = 0; ks < 4; ++ks)
          w1b[nxt][ks][i] = *(const s8v*)&base[(((w * 2 + i) * 4 + ks) * 512) + lane * 8];
    }

    __syncthreads();  // prior GEMM2 Hs reads complete
    // epilogue: relu only (bias folded into ones-column), pack -> b64 write
#pragma unroll
    for (int i = 0; i < 2; ++i)
#pragma unroll
      for (int rt = 0; rt < 4; ++rt) {
        float v0 = fmaxf(h[i][rt][0], 0.f);
        float v1 = fmaxf(h[i][rt][1], 0.f);
        float v2 = fmaxf(h[i][rt][2], 0.f);
        float v3 = fmaxf(h[i][rt][3], 0.f);
        uint2 U; U.x = pk2(v0, v1); U.y = pk2(v2, v3);
        *reinterpret_cast<uint2*>(&Hs[(rt * 8 + w) * 512 + i * 256 + ebase]) = U;
      }
    __syncthreads();

    // GEMM2: a2 = W2(A) x H(B); K=256; agg += relu(a2 + b2)
    f4v a2[2][4];
#pragma unroll
    for (int i = 0; i < 2; ++i)
#pragma unroll
      for (int rt = 0; rt < 4; ++rt) a2[i][rt] = f4v{0.f, 0.f, 0.f, 0.f};
#pragma unroll
    for (int ks = 0; ks < 8; ++ks) {
      s8v hf[4];
#pragma unroll
      for (int rt = 0; rt < 4; ++rt)
        hf[rt] = *(const s8v*)&Hs[(rt * 8 + ks) * 512 + lane * 8];
#pragma unroll
      for (int i = 0; i < 2; ++i)
#pragma unroll
        for (int rt = 0; rt < 4; ++rt)
          a2[i][rt] = __builtin_amdgcn_mfma_f32_16x16x32_bf16(w2f[ks][i], hf[rt], a2[i][rt], 0, 0, 0);
    }
#pragma unroll
    for (int i = 0; i < 2; ++i)
#pragma unroll
      for (int rt = 0; rt < 4; ++rt) {
        agg[i][rt][0] += fmaxf(a2[i][rt][0] + b2v[i].x, 0.f);
        agg[i][rt][1] += fmaxf(a2[i][rt][1] + b2v[i].y, 0.f);
        agg[i][rt][2] += fmaxf(a2[i][rt][2] + b2v[i].z, 0.f);
        agg[i][rt][3] += fmaxf(a2[i][rt][3] + b2v[i].w, 0.f);
      }
  }

  // W3 frags (w2f dead, registers reused)
  s8v w3f[8][2];
#pragma unroll
  for (int i = 0; i < 2; ++i)
#pragma unroll
    for (int ks = 0; ks < 8; ++ks)
      w3f[ks][i] = *(const s8v*)&W3f[(((w * 2 + i) * 8 + ks) * 512) + lane * 8];

  __syncthreads();  // all GEMM2 Hs reads done
#pragma unroll
  for (int i = 0; i < 2; ++i)
#pragma unroll
    for (int rt = 0; rt < 4; ++rt) {
      uint2 U; U.x = pk2(agg[i][rt][0], agg[i][rt][1]);
      U.y = pk2(agg[i][rt][2], agg[i][rt][3]);
      *reinterpret_cast<uint2*>(&Hs[(rt * 8 + w) * 512 + i * 256 + ebase]) = U;
    }
  __syncthreads();

  // GEMM3: hr = relu(W3(A) x agg(B) + b3); K=256
  f4v a3[2][4];
#pragma unroll
  for (int i = 0; i < 2; ++i)
#pragma unroll
    for (int rt = 0; rt < 4; ++rt) a3[i][rt] = f4v{0.f, 0.f, 0.f, 0.f};
#pragma unroll
  for (int ks = 0; ks < 8; ++ks) {
    s8v hf[4];
#pragma unroll
    for (int rt = 0; rt < 4; ++rt)
      hf[rt] = *(const s8v*)&Hs[(rt * 8 + ks) * 512 + lane * 8];
#pragma unroll
    for (int i = 0; i < 2; ++i)
#pragma unroll
      for (int rt = 0; rt < 4; ++rt)
        a3[i][rt] = __builtin_amdgcn_mfma_f32_16x16x32_bf16(w3f[ks][i], hf[rt], a3[i][rt], 0, 0, 0);
  }
  __syncthreads();
#pragma unroll
  for (int i = 0; i < 2; ++i)
#pragma unroll
    for (int rt = 0; rt < 4; ++rt) {
      float v0 = fmaxf(a3[i][rt][0] + b3v[i].x, 0.f);
      float v1 = fmaxf(a3[i][rt][1] + b3v[i].y, 0.f);
      float v2 = fmaxf(a3[i][rt][2] + b3v[i].z, 0.f);
      float v3 = fmaxf(a3[i][rt][3] + b3v[i].w, 0.f);
      uint2 U; U.x = pk2(v0, v1); U.y = pk2(v2, v3);
      *reinterpret_cast<uint2*>(&Hs[(rt * 8 + w) * 512 + i * 256 + ebase]) = U;
    }
  __syncthreads();

  // GEMM4: heads; waves 0..3 take batch tile rt=w
  if (w < 4) {
    f4v a4 = f4v{0.f, 0.f, 0.f, 0.f};
#pragma unroll
    for (int ks = 0; ks < 8; ++ks) {
      s8v w4 = *(const s8v*)&W4f[ks * 512 + lane * 8];
      s8v hf = *(const s8v*)&Hs[(w * 8 + ks) * 512 + lane * 8];
      a4 = __builtin_amdgcn_mfma_f32_16x16x32_bf16(w4, hf, a4, 0, 0, 0);
    }
    const int row = r0 + w * 16 + l15;
    if (quad == 0) {          // head cols 0..3 = mean
      float4 mb = *(const float4*)meanb;
      float4 o;
      o.x = a4[0] + mb.x; o.y = a4[1] + mb.y;
      o.z = a4[2] + mb.z; o.w = a4[3] + mb.w;
      *reinterpret_cast<float4*>(&out[(size_t)row * 4]) = o;
    } else if (quad == 1) {   // head cols 4..7 = logstd (clipped)
      float4 lb = *(const float4*)logstdb;
      float4 o;
      o.x = fminf(fmaxf(a4[0] + lb.x, -20.f), 2.f);
      o.y = fminf(fmaxf(a4[1] + lb.y, -20.f), 2.f);
      o.z = fminf(fmaxf(a4[2] + lb.z, -20.f), 2.f);
      o.w = fminf(fmaxf(a4[3] + lb.w, -20.f), 2.f);
      *reinterpret_cast<float4*>(&out[(size_t)B_TOTAL * 4 + (size_t)row * 4]) = o;
    }
  }
}

extern "C" void kernel_launch(void* const* d_in, const int* in_sizes, int n_in,
                              void* d_out, int out_size, void* d_ws, size_t ws_size,
                              hipStream_t stream) {
  const float* obs      = (const float*)d_in[0];
  const float* ag       = (const float*)d_in[1];
  const float* g        = (const float*)d_in[2];
  const float* phi_w1   = (const float*)d_in[3];
  const float* phi_b1   = (const float*)d_in[4];
  const float* phi_w2   = (const float*)d_in[5];
  const float* phi_b2   = (const float*)d_in[6];
  const float* rho_w1   = (const float*)d_in[7];
  const float* rho_b1   = (const float*)d_in[8];
  const float* mean_w   = (const float*)d_in[9];
  const float* mean_b   = (const float*)d_in[10];
  const float* logstd_w = (const float*)d_in[11];
  const float* logstd_b = (const float*)d_in[12];
  float* out = (float*)d_out;

  // ws (bf16): W1P 6x32768 | W2f 65536 | W3f 65536 | W4f 4096 elems
  char* ws = (char*)d_ws;
  __hip_bfloat16* W1P = (__hip_bfloat16*)(ws);
  __hip_bfloat16* W2f = (__hip_bfloat16*)(ws + 393216);
  __hip_bfloat16* W3f = (__hip_bfloat16*)(ws + 393216 + 131072);
  __hip_bfloat16* W4f = (__hip_bfloat16*)(ws + 393216 + 262144);

  prep_weights<<<256, 256, 0, stream>>>(phi_w1, phi_b1, phi_w2, rho_w1,
                                        mean_w, logstd_w, W1P, W2f, W3f, W4f);
  actor_main<<<B_TOTAL / TROWS, 512, 0, stream>>>(
      obs, ag, g, W1P, W2f, W3f, W4f, phi_b2, rho_b1, mean_b, logstd_b, out);
}

// Round 5
// 192.370 us; speedup vs baseline: 5.1132x; 1.2549x over previous
//
#include <hip/hip_runtime.h>
#include <hip/hip_bf16.h>

// ---------------------------------------------------------------------------
// SemanticActor fused forward, bf16 MFMA (gfx950) — Round 5
// R4 diagnosis: spills returned (WRITE 172MB, FETCH 107MB = whole runtime).
// launch_bounds(512,2) caps VGPR at 128; structure needs ~240.
// Fix: launch_bounds(512,1) -> 256 VGPR cap (1 block/CU), drop W1P double
// buffer (load per pair from L2), pair loop NOT unrolled to stop cross-pair
// load hoisting. Everything else = R4 (weight-permuted gather-free GEMM1,
// frag-major LDS, register-resident W2).
// ---------------------------------------------------------------------------

#define B_TOTAL 65536
#define TROWS   64
#define RSTR    136   // rawS row stride elems: 272 B = 17x16B (odd) -> <=2-way

typedef __attribute__((ext_vector_type(8))) short s8v;   // 8 x bf16
typedef __attribute__((ext_vector_type(4))) float f4v;   // MFMA C/D

__constant__ int c_PI[6] = {0,0,1,1,2,2};
__constant__ int c_PJ[6] = {1,2,0,2,0,1};
__constant__ int c_PF[6] = {0,0,1,0,1,1};
// inverse of FIRST_INDS / SECOND_INDS: raw ag/g col -> X col (or -1)
__constant__ int c_INV[2][30] = {
  {0,1,2,3,4,5,6,7,8,9,10,11,12,13,-1,14,15,16,-1,-1,17,18,-1,-1,-1,19,-1,-1,-1,-1},
  {0,1,2,3,4,5,6,7,8,9,-1,-1,-1,-1,10,-1,-1,-1,11,12,-1,-1,13,14,15,-1,16,17,18,19}};

__global__ void prep_weights(const float* __restrict__ phi_w1,
                             const float* __restrict__ phi_b1,
                             const float* __restrict__ phi_w2,
                             const float* __restrict__ rho_w1,
                             const float* __restrict__ mean_w,
                             const float* __restrict__ logstd_w,
                             __hip_bfloat16* __restrict__ W1P,
                             __hip_bfloat16* __restrict__ W2f,
                             __hip_bfloat16* __restrict__ W3f,
                             __hip_bfloat16* __restrict__ W4f) {
  const int i0 = blockIdx.x * blockDim.x + threadIdx.x;
  const int stride = gridDim.x * blockDim.x;
  // W1P: 6 pairs x (16 nb x 4 ks) x 512; K=128 raw cols via inverse map
  for (int d = i0; d < 6 * 32768; d += stride) {
    int p = d >> 15, r = d & 32767;
    int j = r & 7, lane = (r >> 3) & 63, blk = r >> 9;
    int nb = blk >> 2, ks = blk & 3;
    int n = nb * 16 + (lane & 15), k = ks * 32 + (lane >> 4) * 8 + j;
    int f = c_PF[p], oi = c_PI[p], oj = c_PJ[p];
    float v = 0.0f;
    if (k < 30)       { int t = c_INV[f][k];      if (t >= 0) v = phi_w1[t * 256 + n]; }
    else if (k < 60)  { int t = c_INV[f][k - 30]; if (t >= 0) v = phi_w1[(30 + t) * 256 + n]; }
    else if (k < 70)  { v = phi_w1[(20 + k - 60) * 256 + n]; }
    else if (k < 115) { int q = (k - 70) / 15, t = (k - 70) - q * 15;
                        int c = (q == oi) ? 50 + t : (q == oj) ? 65 + t : -1;
                        if (c >= 0) v = phi_w1[c * 256 + n]; }
    else if (k == 115) v = phi_b1[n];   // bias via ones-column
    W1P[d] = __float2bfloat16(v);
  }
  // W2f/W3f: 16 nb x 8 ks, 256x256
  for (int d = i0; d < 65536; d += stride) {
    int j = d & 7, lane = (d >> 3) & 63, blk = d >> 9;
    int nb = blk >> 3, ks = blk & 7;
    int n = nb * 16 + (lane & 15), k = ks * 32 + (lane >> 4) * 8 + j;
    W2f[d] = __float2bfloat16(phi_w2[k * 256 + n]);
    W3f[d] = __float2bfloat16(rho_w1[k * 256 + n]);
  }
  // W4f: 1 nb (16 head cols: 0-3 mean, 4-7 logstd, rest 0) x 8 ks
  for (int d = i0; d < 4096; d += stride) {
    int j = d & 7, lane = (d >> 3) & 63, ks = d >> 9;
    int n = lane & 15, k = ks * 32 + (lane >> 4) * 8 + j;
    float v = (n < 4) ? mean_w[k * 4 + n]
            : (n < 8) ? logstd_w[k * 4 + (n - 4)] : 0.0f;
    W4f[d] = __float2bfloat16(v);
  }
}

static __device__ __forceinline__ unsigned pk2(float a, float b) {
  __hip_bfloat162 h = __float22bfloat162_rn(float2{a, b});
  union { __hip_bfloat162 h2; unsigned u; } cv; cv.h2 = h;
  return cv.u;
}

// ---- main: 512 threads (8 waves), 64 rows/block, wave = 32-col slice -------
__global__ __launch_bounds__(512, 1)
void actor_main(const float* __restrict__ obs, const float* __restrict__ ag,
                const float* __restrict__ g,
                const __hip_bfloat16* __restrict__ W1P,
                const __hip_bfloat16* __restrict__ W2f,
                const __hip_bfloat16* __restrict__ W3f,
                const __hip_bfloat16* __restrict__ W4f,
                const float* __restrict__ b2, const float* __restrict__ b3,
                const float* __restrict__ meanb,
                const float* __restrict__ logstdb,
                float* __restrict__ out) {
  __shared__ __align__(16) __hip_bfloat16 rawS[TROWS * RSTR];  // 17.4 KB
  __shared__ __align__(16) __hip_bfloat16 Hs[4 * 8 * 512];     // 32 KB

  const int tid  = threadIdx.x;
  const int lane = tid & 63;
  const int w    = tid >> 6;      // wave 0..7 -> hidden cols [32w, 32w+32)
  const int l15  = lane & 15;
  const int quad = lane >> 4;
  const int r0   = blockIdx.x * TROWS;

  float4 b2v[2], b3v[2];
#pragma unroll
  for (int i = 0; i < 2; ++i) {
    int col0 = w * 32 + i * 16 + quad * 4;
    b2v[i] = *(const float4*)&b2[col0];
    b3v[i] = *(const float4*)&b3[col0];
  }

  // persistent W2 fragments (once per block)
  s8v w2f[8][2];
#pragma unroll
  for (int i = 0; i < 2; ++i)
#pragma unroll
    for (int ks = 0; ks < 8; ++ks)
      w2f[ks][i] = *(const s8v*)&W2f[(((w * 2 + i) * 8 + ks) * 512) + lane * 8];

  // stage raw input [ag|g|obs|1|0] as bf16, K=128, once per block
  {
    const int row = tid >> 3;           // 0..63
    const int c0  = (tid & 7) * 16;     // 0..112
    const float* agr = ag  + (size_t)(r0 + row) * 30;
    const float* gr  = g   + (size_t)(r0 + row) * 30;
    const float* obr = obs + (size_t)(r0 + row) * 55;
#pragma unroll
    for (int cc = 0; cc < 16; ++cc) {
      int c = c0 + cc;
      float v;
      if      (c < 30)  v = agr[c];
      else if (c < 60)  v = gr[c - 30];
      else if (c < 115) v = obr[c - 60];
      else if (c == 115) v = 1.0f;
      else              v = 0.0f;
      rawS[row * RSTR + c] = __float2bfloat16(v);
    }
  }

  f4v agg[2][4];
#pragma unroll
  for (int i = 0; i < 2; ++i)
#pragma unroll
    for (int rt = 0; rt < 4; ++rt) agg[i][rt] = f4v{0.f, 0.f, 0.f, 0.f};

  const int ebase = l15 * 8 + (quad >> 1) * 128 + (quad & 1) * 4;

  __syncthreads();  // rawS staged

#pragma unroll 1
  for (int p = 0; p < 6; ++p) {
    // load this pair's W1P frags (L2-resident, used once)
    s8v w1f[4][2];
    {
      const __hip_bfloat16* base = W1P + p * 32768;
#pragma unroll
      for (int i = 0; i < 2; ++i)
#pragma unroll
        for (int ks = 0; ks < 4; ++ks)
          w1f[ks][i] = *(const s8v*)&base[(((w * 2 + i) * 4 + ks) * 512) + lane * 8];
    }

    // GEMM1: h = W1P[p](A) x raw(B); K=128
    f4v h[2][4];
#pragma unroll
    for (int i = 0; i < 2; ++i)
#pragma unroll
      for (int rt = 0; rt < 4; ++rt) h[i][rt] = f4v{0.f, 0.f, 0.f, 0.f};
#pragma unroll
    for (int ks = 0; ks < 4; ++ks) {
      s8v bx[4];
#pragma unroll
      for (int rt = 0; rt < 4; ++rt)
        bx[rt] = *(const s8v*)&rawS[(rt * 16 + l15) * RSTR + ks * 32 + quad * 8];
#pragma unroll
      for (int i = 0; i < 2; ++i)
#pragma unroll
        for (int rt = 0; rt < 4; ++rt)
          h[i][rt] = __builtin_amdgcn_mfma_f32_16x16x32_bf16(w1f[ks][i], bx[rt], h[i][rt], 0, 0, 0);
    }

    __syncthreads();  // prior GEMM2 Hs reads complete
    // epilogue: relu only (bias folded into ones-column), pack -> b64 write
#pragma unroll
    for (int i = 0; i < 2; ++i)
#pragma unroll
      for (int rt = 0; rt < 4; ++rt) {
        float v0 = fmaxf(h[i][rt][0], 0.f);
        float v1 = fmaxf(h[i][rt][1], 0.f);
        float v2 = fmaxf(h[i][rt][2], 0.f);
        float v3 = fmaxf(h[i][rt][3], 0.f);
        uint2 U; U.x = pk2(v0, v1); U.y = pk2(v2, v3);
        *reinterpret_cast<uint2*>(&Hs[(rt * 8 + w) * 512 + i * 256 + ebase]) = U;
      }
    __syncthreads();

    // GEMM2: a2 = W2(A) x H(B); K=256; agg += relu(a2 + b2)
    f4v a2[2][4];
#pragma unroll
    for (int i = 0; i < 2; ++i)
#pragma unroll
      for (int rt = 0; rt < 4; ++rt) a2[i][rt] = f4v{0.f, 0.f, 0.f, 0.f};
#pragma unroll
    for (int ks = 0; ks < 8; ++ks) {
      s8v hf[4];
#pragma unroll
      for (int rt = 0; rt < 4; ++rt)
        hf[rt] = *(const s8v*)&Hs[(rt * 8 + ks) * 512 + lane * 8];
#pragma unroll
      for (int i = 0; i < 2; ++i)
#pragma unroll
        for (int rt = 0; rt < 4; ++rt)
          a2[i][rt] = __builtin_amdgcn_mfma_f32_16x16x32_bf16(w2f[ks][i], hf[rt], a2[i][rt], 0, 0, 0);
    }
#pragma unroll
    for (int i = 0; i < 2; ++i)
#pragma unroll
      for (int rt = 0; rt < 4; ++rt) {
        agg[i][rt][0] += fmaxf(a2[i][rt][0] + b2v[i].x, 0.f);
        agg[i][rt][1] += fmaxf(a2[i][rt][1] + b2v[i].y, 0.f);
        agg[i][rt][2] += fmaxf(a2[i][rt][2] + b2v[i].z, 0.f);
        agg[i][rt][3] += fmaxf(a2[i][rt][3] + b2v[i].w, 0.f);
      }
  }

  // W3 frags (w2f dead, registers reused)
  s8v w3f[8][2];
#pragma unroll
  for (int i = 0; i < 2; ++i)
#pragma unroll
    for (int ks = 0; ks < 8; ++ks)
      w3f[ks][i] = *(const s8v*)&W3f[(((w * 2 + i) * 8 + ks) * 512) + lane * 8];

  __syncthreads();  // all GEMM2 Hs reads done
#pragma unroll
  for (int i = 0; i < 2; ++i)
#pragma unroll
    for (int rt = 0; rt < 4; ++rt) {
      uint2 U; U.x = pk2(agg[i][rt][0], agg[i][rt][1]);
      U.y = pk2(agg[i][rt][2], agg[i][rt][3]);
      *reinterpret_cast<uint2*>(&Hs[(rt * 8 + w) * 512 + i * 256 + ebase]) = U;
    }
  __syncthreads();

  // GEMM3: hr = relu(W3(A) x agg(B) + b3); K=256
  f4v a3[2][4];
#pragma unroll
  for (int i = 0; i < 2; ++i)
#pragma unroll
    for (int rt = 0; rt < 4; ++rt) a3[i][rt] = f4v{0.f, 0.f, 0.f, 0.f};
#pragma unroll
  for (int ks = 0; ks < 8; ++ks) {
    s8v hf[4];
#pragma unroll
    for (int rt = 0; rt < 4; ++rt)
      hf[rt] = *(const s8v*)&Hs[(rt * 8 + ks) * 512 + lane * 8];
#pragma unroll
    for (int i = 0; i < 2; ++i)
#pragma unroll
      for (int rt = 0; rt < 4; ++rt)
        a3[i][rt] = __builtin_amdgcn_mfma_f32_16x16x32_bf16(w3f[ks][i], hf[rt], a3[i][rt], 0, 0, 0);
  }
  __syncthreads();
#pragma unroll
  for (int i = 0; i < 2; ++i)
#pragma unroll
    for (int rt = 0; rt < 4; ++rt) {
      float v0 = fmaxf(a3[i][rt][0] + b3v[i].x, 0.f);
      float v1 = fmaxf(a3[i][rt][1] + b3v[i].y, 0.f);
      float v2 = fmaxf(a3[i][rt][2] + b3v[i].z, 0.f);
      float v3 = fmaxf(a3[i][rt][3] + b3v[i].w, 0.f);
      uint2 U; U.x = pk2(v0, v1); U.y = pk2(v2, v3);
      *reinterpret_cast<uint2*>(&Hs[(rt * 8 + w) * 512 + i * 256 + ebase]) = U;
    }
  __syncthreads();

  // GEMM4: heads; waves 0..3 take batch tile rt=w
  if (w < 4) {
    f4v a4 = f4v{0.f, 0.f, 0.f, 0.f};
#pragma unroll
    for (int ks = 0; ks < 8; ++ks) {
      s8v w4 = *(const s8v*)&W4f[ks * 512 + lane * 8];
      s8v hf = *(const s8v*)&Hs[(w * 8 + ks) * 512 + lane * 8];
      a4 = __builtin_amdgcn_mfma_f32_16x16x32_bf16(w4, hf, a4, 0, 0, 0);
    }
    const int row = r0 + w * 16 + l15;
    if (quad == 0) {          // head cols 0..3 = mean
      float4 mb = *(const float4*)meanb;
      float4 o;
      o.x = a4[0] + mb.x; o.y = a4[1] + mb.y;
      o.z = a4[2] + mb.z; o.w = a4[3] + mb.w;
      *reinterpret_cast<float4*>(&out[(size_t)row * 4]) = o;
    } else if (quad == 1) {   // head cols 4..7 = logstd (clipped)
      float4 lb = *(const float4*)logstdb;
      float4 o;
      o.x = fminf(fmaxf(a4[0] + lb.x, -20.f), 2.f);
      o.y = fminf(fmaxf(a4[1] + lb.y, -20.f), 2.f);
      o.z = fminf(fmaxf(a4[2] + lb.z, -20.f), 2.f);
      o.w = fminf(fmaxf(a4[3] + lb.w, -20.f), 2.f);
      *reinterpret_cast<float4*>(&out[(size_t)B_TOTAL * 4 + (size_t)row * 4]) = o;
    }
  }
}

extern "C" void kernel_launch(void* const* d_in, const int* in_sizes, int n_in,
                              void* d_out, int out_size, void* d_ws, size_t ws_size,
                              hipStream_t stream) {
  const float* obs      = (const float*)d_in[0];
  const float* ag       = (const float*)d_in[1];
  const float* g        = (const float*)d_in[2];
  const float* phi_w1   = (const float*)d_in[3];
  const float* phi_b1   = (const float*)d_in[4];
  const float* phi_w2   = (const float*)d_in[5];
  const float* phi_b2   = (const float*)d_in[6];
  const float* rho_w1   = (const float*)d_in[7];
  const float* rho_b1   = (const float*)d_in[8];
  const float* mean_w   = (const float*)d_in[9];
  const float* mean_b   = (const float*)d_in[10];
  const float* logstd_w = (const float*)d_in[11];
  const float* logstd_b = (const float*)d_in[12];
  float* out = (float*)d_out;

  // ws (bf16): W1P 6x32768 | W2f 65536 | W3f 65536 | W4f 4096 elems
  char* ws = (char*)d_ws;
  __hip_bfloat16* W1P = (__hip_bfloat16*)(ws);
  __hip_bfloat16* W2f = (__hip_bfloat16*)(ws + 393216);
  __hip_bfloat16* W3f = (__hip_bfloat16*)(ws + 393216 + 131072);
  __hip_bfloat16* W4f = (__hip_bfloat16*)(ws + 393216 + 262144);

  prep_weights<<<256, 256, 0, stream>>>(phi_w1, phi_b1, phi_w2, rho_w1,
                                        mean_w, logstd_w, W1P, W2f, W3f, W4f);
  actor_main<<<B_TOTAL / TROWS, 512, 0, stream>>>(
      obs, ag, g, W1P, W2f, W3f, W4f, phi_b2, rho_b1, mean_b, logstd_b, out);
}